// Round 1
// baseline (490.481 us; speedup 1.0000x reference)
//
#include <hip/hip_runtime.h>

// Problem constants (fixed by setup_inputs)
#define N_PAIRS   300000
#define N_CENTERS 10000
#define N_FEAT    1280   // sum over l of (2l+1)*4*20 = 16*80
#define PF        4      // pairs staged per barrier round

// -------- phase A: counting sort of pairs by center --------

__global__ void hist_k(const int* __restrict__ didx, int* __restrict__ counts) {
    int p = blockIdx.x * blockDim.x + threadIdx.x;
    if (p < N_PAIRS) atomicAdd(&counts[didx[p]], 1);
}

__global__ void scan_k(const int* __restrict__ counts,
                       int* __restrict__ offsets, int* __restrict__ cursor) {
    __shared__ int part[1024];
    int t = threadIdx.x;
    const int CH = 10;                 // 1024*10 = 10240 >= N_CENTERS
    int base = t * CH;
    int loc[CH];
    int s = 0;
    #pragma unroll
    for (int j = 0; j < CH; ++j) {
        int v = (base + j < N_CENTERS) ? counts[base + j] : 0;
        loc[j] = s; s += v;            // local exclusive prefix
    }
    part[t] = s;
    __syncthreads();
    // Hillis-Steele inclusive scan over 1024 partials
    for (int off = 1; off < 1024; off <<= 1) {
        int v   = part[t];
        int add = (t >= off) ? part[t - off] : 0;
        __syncthreads();
        part[t] = v + add;
        __syncthreads();
    }
    int prefix = (t > 0) ? part[t - 1] : 0;
    #pragma unroll
    for (int j = 0; j < CH; ++j) {
        int idx = base + j;
        if (idx < N_CENTERS) {
            int o = prefix + loc[j];
            offsets[idx] = o;
            cursor[idx]  = o;
        }
    }
    if (t == 1023) offsets[N_CENTERS] = part[1023];
}

__global__ void scatter_k(const int* __restrict__ didx,
                          int* __restrict__ cursor, int* __restrict__ pair_ids) {
    int p = blockIdx.x * blockDim.x + threadIdx.x;
    if (p < N_PAIRS) {
        int c = didx[p];
        int pos = atomicAdd(&cursor[c], 1);
        pair_ids[pos] = p;
    }
}

// -------- phase B: one block per center, register accumulation --------
// thread t = (d = t/80, u = t%80); owns features f0..f0+3 (same d,
// consecutive g = 4u..4u+3; all (l,c)-boundaries are multiples of 4 so a
// float4 chunk never straddles one).

__global__ __launch_bounds__(320) void accum_k(
    const float* __restrict__ vec0, const float* __restrict__ vec1,
    const float* __restrict__ vec2, const float* __restrict__ vec3,
    const float* __restrict__ W,    const int* __restrict__ species,
    const int* __restrict__ offsets, const int* __restrict__ pair_ids,
    float* __restrict__ out) {
    __shared__ float  ldsW[16];        // W[d][s]
    __shared__ float  ldsWp[PF * 4];   // per staged pair: w[d] = W[d][s_p]
    __shared__ float4 ldsv[PF * 80];   // per staged pair: 320 vec floats

    const int t = threadIdx.x;
    const int c = blockIdx.x;
    if (t < 16) ldsW[t] = W[t];

    const int q = t / 80;              // d for compute; pair-slot for load
    const int u = t - q * 80;          // float4 chunk / feature group

    // loop-invariant load source: which l-array and which float4 of the row
    const float* src; int rowlen, foff;
    if (u < 5)       { src = vec0; rowlen = 20;  foff = u;      }
    else if (u < 20) { src = vec1; rowlen = 60;  foff = u - 5;  }
    else if (u < 45) { src = vec2; rowlen = 100; foff = u - 20; }
    else             { src = vec3; rowlen = 140; foff = u - 45; }

    // loop-invariant output feature index: g0 = 4u -> (l, cc, n0)
    const int g0 = 4 * u;
    int fb, vb;
    if (g0 < 20)       { fb = 0;   vb = 0;   }
    else if (g0 < 80)  { fb = 80;  vb = 20;  }
    else if (g0 < 180) { fb = 320; vb = 80;  }
    else               { fb = 720; vb = 180; }
    const int rr = g0 - vb;
    const int cc = rr / 20;
    const int n0 = rr - cc * 20;
    const int f0 = fb + cc * 80 + q * 20 + n0;   // q plays the role of d

    float4 acc = make_float4(0.f, 0.f, 0.f, 0.f);
    const int start = offsets[c];
    const int end   = offsets[c + 1];
    __syncthreads();                   // ldsW ready

    for (int i0 = start; i0 < end; i0 += PF) {
        const int i = i0 + q;
        if (i < end) {
            const int p = pair_ids[i];
            const float4* s4 = (const float4*)(src + (long long)p * rowlen);
            ldsv[q * 80 + u] = s4[foff];
            if (u == 0) {              // 4 threads also stage the weights
                const int s = species[p];
                ldsWp[q * 4 + 0] = ldsW[0 * 4 + s];
                ldsWp[q * 4 + 1] = ldsW[1 * 4 + s];
                ldsWp[q * 4 + 2] = ldsW[2 * 4 + s];
                ldsWp[q * 4 + 3] = ldsW[3 * 4 + s];
            }
        }
        __syncthreads();
        const int nq = min(PF, end - i0);
        for (int q2 = 0; q2 < nq; ++q2) {
            const float  w = ldsWp[q2 * 4 + q];   // broadcast ds_read_b32
            const float4 v = ldsv[q2 * 80 + u];   // ds_read_b128
            acc.x += v.x * w; acc.y += v.y * w;
            acc.z += v.z * w; acc.w += v.w * w;
        }
        __syncthreads();
    }
    // one coalesced float4 store per thread; empty centers write zeros
    ((float4*)(out + (long long)c * N_FEAT))[f0 >> 2] = acc;
}

// -------- launcher --------
extern "C" void kernel_launch(void* const* d_in, const int* in_sizes, int n_in,
                              void* d_out, int out_size, void* d_ws, size_t ws_size,
                              hipStream_t stream) {
    const float* vec0 = (const float*)d_in[0];
    const float* vec1 = (const float*)d_in[1];
    const float* vec2 = (const float*)d_in[2];
    const float* vec3 = (const float*)d_in[3];
    const float* W    = (const float*)d_in[4];
    const int* species = (const int*)d_in[5];
    const int* didx    = (const int*)d_in[6];
    float* out = (float*)d_out;

    int* ws       = (int*)d_ws;
    int* counts   = ws;            // N_CENTERS
    int* offsets  = ws + 16384;    // N_CENTERS + 1
    int* cursor   = ws + 32768;    // N_CENTERS
    int* pair_ids = ws + 49152;    // N_PAIRS
    // total: 49152 + 300000 ints = ~1.4 MB of d_ws

    hipMemsetAsync(counts, 0, N_CENTERS * sizeof(int), stream);
    const int nb = (N_PAIRS + 255) / 256;
    hist_k   <<<nb, 256, 0, stream>>>(didx, counts);
    scan_k   <<<1, 1024, 0, stream>>>(counts, offsets, cursor);
    scatter_k<<<nb, 256, 0, stream>>>(didx, cursor, pair_ids);
    accum_k  <<<N_CENTERS, 320, 0, stream>>>(vec0, vec1, vec2, vec3, W, species,
                                             offsets, pair_ids, out);
}

// Round 2
// 462.264 us; speedup vs baseline: 1.0610x; 1.0610x over previous
//
#include <hip/hip_runtime.h>

// Problem constants (fixed by setup_inputs)
#define N_PAIRS   300000
#define N_CENTERS 10000
#define N_FEAT    1280   // sum over l of (2l+1)*4*20 = 16*80

// -------- phase A: counting sort of pairs by center --------
// counters/cursors padded by `pad` ints (64B line) to kill same-line atomic serialization

__global__ void hist_k(const int* __restrict__ didx, int* __restrict__ counts, int pad) {
    int p = blockIdx.x * blockDim.x + threadIdx.x;
    if (p < N_PAIRS) atomicAdd(&counts[didx[p] * pad], 1);
}

__global__ void scan_k(const int* __restrict__ counts,
                       int* __restrict__ offsets, int* __restrict__ cursor, int pad) {
    __shared__ int part[1024];
    int t = threadIdx.x;
    const int CH = 10;                 // 1024*10 = 10240 >= N_CENTERS
    int base = t * CH;
    int loc[CH];
    int s = 0;
    #pragma unroll
    for (int j = 0; j < CH; ++j) {
        int v = (base + j < N_CENTERS) ? counts[(base + j) * pad] : 0;
        loc[j] = s; s += v;            // local exclusive prefix
    }
    part[t] = s;
    __syncthreads();
    for (int off = 1; off < 1024; off <<= 1) {
        int v   = part[t];
        int add = (t >= off) ? part[t - off] : 0;
        __syncthreads();
        part[t] = v + add;
        __syncthreads();
    }
    int prefix = (t > 0) ? part[t - 1] : 0;
    #pragma unroll
    for (int j = 0; j < CH; ++j) {
        int idx = base + j;
        if (idx < N_CENTERS) {
            int o = prefix + loc[j];
            offsets[idx] = o;
            cursor[idx * pad] = o;
        }
    }
    if (t == 1023) offsets[N_CENTERS] = part[1023];
}

__global__ void scatter_k(const int* __restrict__ didx, const int* __restrict__ species,
                          int* __restrict__ cursor, int* __restrict__ pairs, int pad) {
    int p = blockIdx.x * blockDim.x + threadIdx.x;
    if (p < N_PAIRS) {
        int c = didx[p];
        int pos = atomicAdd(&cursor[c * pad], 1);
        pairs[pos] = p | (species[p] << 20);   // p < 2^19, s < 4
    }
}

// -------- phase B: one block per center, no LDS, no barriers --------
// thread t = (d = t&3, u = t>>2). 4 consecutive lanes load the SAME float4
// (coalescer merges same-address lanes -> 1x memory traffic). Each thread
// owns features f0..f0+3 = (l,cc,d,n0..n0+3); float4 chunks never straddle
// an (l,c) boundary (all boundaries are multiples of 4 floats).

__global__ __launch_bounds__(320) void accum_k(
    const float* __restrict__ vec0, const float* __restrict__ vec1,
    const float* __restrict__ vec2, const float* __restrict__ vec3,
    const float* __restrict__ W,
    const int* __restrict__ offsets, const int* __restrict__ pairs,
    float* __restrict__ out) {
    const int t = threadIdx.x;
    const int c = blockIdx.x;
    const int d = t & 3;
    const int u = t >> 2;              // 0..79: which float4 chunk of the pair row

    const float4* src4; int s4len, foff;
    if (u < 5)       { src4 = (const float4*)vec0; s4len = 5;  foff = u;      }
    else if (u < 20) { src4 = (const float4*)vec1; s4len = 15; foff = u - 5;  }
    else if (u < 45) { src4 = (const float4*)vec2; s4len = 25; foff = u - 20; }
    else             { src4 = (const float4*)vec3; s4len = 35; foff = u - 45; }

    // output feature index for g0 = 4u
    const int g0 = 4 * u;
    int fb, vb;
    if (g0 < 20)       { fb = 0;   vb = 0;   }
    else if (g0 < 80)  { fb = 80;  vb = 20;  }
    else if (g0 < 180) { fb = 320; vb = 80;  }
    else               { fb = 720; vb = 180; }
    const int rr = g0 - vb;
    const int cc = rr / 20;
    const int n0 = rr - cc * 20;
    const int f0 = fb + cc * 80 + d * 20 + n0;

    // W[d][s] in registers; select by species with cndmasks
    const float w0 = W[d * 4 + 0], w1 = W[d * 4 + 1];
    const float w2 = W[d * 4 + 2], w3 = W[d * 4 + 3];

    float4 acc = make_float4(0.f, 0.f, 0.f, 0.f);
    int i = offsets[c];
    const int end = offsets[c + 1];

    #define LOADV(pk, v, w)                                            \
        {   int p_ = (pk) & 0xFFFFF;                                   \
            int s_ = (pk) >> 20;                                       \
            v = src4[(long long)p_ * s4len + foff];                    \
            w = (s_ == 0) ? w0 : (s_ == 1) ? w1 : (s_ == 2) ? w2 : w3; }

    for (; i + 4 <= end; i += 4) {
        const int pk0 = pairs[i], pk1 = pairs[i + 1];
        const int pk2 = pairs[i + 2], pk3 = pairs[i + 3];
        float4 v0, v1, v2, v3; float a0, a1, a2, a3;
        LOADV(pk0, v0, a0); LOADV(pk1, v1, a1);
        LOADV(pk2, v2, a2); LOADV(pk3, v3, a3);
        acc.x += v0.x * a0; acc.y += v0.y * a0; acc.z += v0.z * a0; acc.w += v0.w * a0;
        acc.x += v1.x * a1; acc.y += v1.y * a1; acc.z += v1.z * a1; acc.w += v1.w * a1;
        acc.x += v2.x * a2; acc.y += v2.y * a2; acc.z += v2.z * a2; acc.w += v2.w * a2;
        acc.x += v3.x * a3; acc.y += v3.y * a3; acc.z += v3.z * a3; acc.w += v3.w * a3;
    }
    for (; i < end; ++i) {
        const int pk = pairs[i];
        float4 v; float a;
        LOADV(pk, v, a);
        acc.x += v.x * a; acc.y += v.y * a; acc.z += v.z * a; acc.w += v.w * a;
    }
    #undef LOADV

    ((float4*)(out + (long long)c * N_FEAT))[f0 >> 2] = acc;
}

// -------- launcher --------
extern "C" void kernel_launch(void* const* d_in, const int* in_sizes, int n_in,
                              void* d_out, int out_size, void* d_ws, size_t ws_size,
                              hipStream_t stream) {
    const float* vec0 = (const float*)d_in[0];
    const float* vec1 = (const float*)d_in[1];
    const float* vec2 = (const float*)d_in[2];
    const float* vec3 = (const float*)d_in[3];
    const float* W    = (const float*)d_in[4];
    const int* species = (const int*)d_in[5];
    const int* didx    = (const int*)d_in[6];
    float* out = (float*)d_out;

    // pick counter padding from available workspace (ws_size is fixed across
    // calls, so this branch is deterministic / graph-safe)
    // layout: counts [N_CENTERS*pad] | cursor [N_CENTERS*pad] | offsets [N_CENTERS+1] | pairs [N_PAIRS]
    size_t fixed = (size_t)(N_CENTERS + 1 + N_PAIRS) * 4;
    int pad = 1;
    if (ws_size >= fixed + (size_t)2 * N_CENTERS * 16 * 4 + 4096) pad = 16;
    else if (ws_size >= fixed + (size_t)2 * N_CENTERS * 4 * 4 + 4096) pad = 4;

    int* ws       = (int*)d_ws;
    int* counts   = ws;
    int* cursor   = counts + (size_t)N_CENTERS * pad;
    int* offsets  = cursor + (size_t)N_CENTERS * pad;
    int* pairs    = offsets + (N_CENTERS + 1);

    hipMemsetAsync(counts, 0, (size_t)N_CENTERS * pad * sizeof(int), stream);
    const int nb = (N_PAIRS + 255) / 256;
    hist_k   <<<nb, 256, 0, stream>>>(didx, counts, pad);
    scan_k   <<<1, 1024, 0, stream>>>(counts, offsets, cursor, pad);
    scatter_k<<<nb, 256, 0, stream>>>(didx, species, cursor, pairs, pad);
    accum_k  <<<N_CENTERS, 320, 0, stream>>>(vec0, vec1, vec2, vec3, W,
                                             offsets, pairs, out);
}

// Round 3
// 431.624 us; speedup vs baseline: 1.1364x; 1.0710x over previous
//
#include <hip/hip_runtime.h>

// Problem constants (fixed by setup_inputs)
#define N_PAIRS   300000
#define N_CENTERS 10000
#define N_FEAT    1280   // sum over l of (2l+1)*4*20 = 16*80

// -------- phase A: capacity-bucket counting sort (no hist, no scan) --------
// cursor[c*padc] counts pairs of center c; pairs[c*cap + pos] = p | s<<20.

__global__ void scatter_k(const int* __restrict__ didx, const int* __restrict__ species,
                          int* __restrict__ cursor, int* __restrict__ pairs,
                          int cap, int padc) {
    int p = blockIdx.x * blockDim.x + threadIdx.x;
    if (p < N_PAIRS) {
        int c = didx[p];
        int pos = atomicAdd(&cursor[c * padc], 1);
        if (pos < cap) pairs[c * cap + pos] = p | (species[p] << 20);  // p < 2^19, s < 4
    }
}

// -------- phase B: one block per center, no LDS, no barriers --------
// thread t = (d = t&3, u = t>>2). 4 consecutive lanes load the SAME float4
// (coalescer merges). 8 pairs per round, pair-list int4 reads software-
// pipelined; tail handled in-register (stale slots clamped + zero weight).

__global__ __launch_bounds__(320) void accum_k(
    const float* __restrict__ vec0, const float* __restrict__ vec1,
    const float* __restrict__ vec2, const float* __restrict__ vec3,
    const float* __restrict__ W,
    const int* __restrict__ cursor, const int* __restrict__ pairs,
    float* __restrict__ out, int cap, int padc) {
    const int t = threadIdx.x;
    const int c = blockIdx.x;
    const int d = t & 3;
    const int u = t >> 2;              // 0..79: which float4 chunk of the pair row

    const float4* src4; int s4len, foff;
    if (u < 5)       { src4 = (const float4*)vec0; s4len = 5;  foff = u;      }
    else if (u < 20) { src4 = (const float4*)vec1; s4len = 15; foff = u - 5;  }
    else if (u < 45) { src4 = (const float4*)vec2; s4len = 25; foff = u - 20; }
    else             { src4 = (const float4*)vec3; s4len = 35; foff = u - 45; }

    // output feature index for g0 = 4u
    const int g0 = 4 * u;
    int fb, vb;
    if (g0 < 20)       { fb = 0;   vb = 0;   }
    else if (g0 < 80)  { fb = 80;  vb = 20;  }
    else if (g0 < 180) { fb = 320; vb = 80;  }
    else               { fb = 720; vb = 180; }
    const int rr = g0 - vb;
    const int cc = rr / 20;
    const int n0 = rr - cc * 20;
    const int f0 = fb + cc * 80 + d * 20 + n0;

    // W[d][s] in registers
    const float w0 = W[d * 4 + 0], w1 = W[d * 4 + 1];
    const float w2 = W[d * 4 + 2], w3 = W[d * 4 + 3];

    int cnt = cursor[c * padc];
    cnt = min(cnt, cap);
    const int* pb = pairs + c * cap;   // 32B-aligned (cap multiple of 8)

    float4 acc = make_float4(0.f, 0.f, 0.f, 0.f);

    // prologue prefetch (always safe: pairs region has >=32 ints of slack)
    int4 pka = ((const int4*)pb)[0];
    int4 pkb = ((const int4*)pb)[1];

    #define G(pk, vv, ww, valid)                                   \
        {   int p_ = (pk) & 0xFFFFF;                               \
            p_ = min(p_, N_PAIRS - 1);                             \
            vv = src4[(long long)p_ * s4len + foff];               \
            int s_ = ((pk) >> 20) & 3;                             \
            float w_ = (s_ == 0) ? w0 : (s_ == 1) ? w1              \
                     : (s_ == 2) ? w2 : w3;                        \
            ww = (valid) ? w_ : 0.f; }

    for (int i = 0; i < cnt; i += 8) {
        const int4 ca = pka, cb = pkb;
        float4 v0, v1, v2, v3, v4, v5, v6, v7;
        float  a0, a1, a2, a3, a4, a5, a6, a7;
        const int rem = cnt - i;       // >=1
        G(ca.x, v0, a0, true);
        G(ca.y, v1, a1, rem > 1);
        G(ca.z, v2, a2, rem > 2);
        G(ca.w, v3, a3, rem > 3);
        G(cb.x, v4, a4, rem > 4);
        G(cb.y, v5, a5, rem > 5);
        G(cb.z, v6, a6, rem > 6);
        G(cb.w, v7, a7, rem > 7);
        // prefetch next round's pair words while gathers are in flight
        const int4* nx = (const int4*)(pb + i + 8);
        pka = nx[0];
        pkb = nx[1];
        acc.x += v0.x * a0; acc.y += v0.y * a0; acc.z += v0.z * a0; acc.w += v0.w * a0;
        acc.x += v1.x * a1; acc.y += v1.y * a1; acc.z += v1.z * a1; acc.w += v1.w * a1;
        acc.x += v2.x * a2; acc.y += v2.y * a2; acc.z += v2.z * a2; acc.w += v2.w * a2;
        acc.x += v3.x * a3; acc.y += v3.y * a3; acc.z += v3.z * a3; acc.w += v3.w * a3;
        acc.x += v4.x * a4; acc.y += v4.y * a4; acc.z += v4.z * a4; acc.w += v4.w * a4;
        acc.x += v5.x * a5; acc.y += v5.y * a5; acc.z += v5.z * a5; acc.w += v5.w * a5;
        acc.x += v6.x * a6; acc.y += v6.y * a6; acc.z += v6.z * a6; acc.w += v6.w * a6;
        acc.x += v7.x * a7; acc.y += v7.y * a7; acc.z += v7.z * a7; acc.w += v7.w * a7;
    }
    #undef G

    ((float4*)(out + (long long)c * N_FEAT))[f0 >> 2] = acc;
}

// -------- launcher --------
extern "C" void kernel_launch(void* const* d_in, const int* in_sizes, int n_in,
                              void* d_out, int out_size, void* d_ws, size_t ws_size,
                              hipStream_t stream) {
    const float* vec0 = (const float*)d_in[0];
    const float* vec1 = (const float*)d_in[1];
    const float* vec2 = (const float*)d_in[2];
    const float* vec3 = (const float*)d_in[3];
    const float* W    = (const float*)d_in[4];
    const int* species = (const int*)d_in[5];
    const int* didx    = (const int*)d_in[6];
    float* out = (float*)d_out;

    // pick bucket capacity + cursor padding from ws_size (fixed across calls
    // -> deterministic, graph-safe). layout: cursor [N_CENTERS*padc] |
    // pairs [N_CENTERS*cap + 32 slack]
    int cap = 256, padc = 16;
    auto need = [](int cap_, int padc_) {
        return ((size_t)N_CENTERS * padc_ + (size_t)N_CENTERS * cap_ + 32) * 4;
    };
    if (ws_size < need(256, 16)) { cap = 128; padc = 16; }
    if (ws_size < need(128, 16)) { cap = 128; padc = 1;  }
    if (ws_size < need(128, 1))  { cap = 64;  padc = 1;  }

    int* cursor = (int*)d_ws;
    int* pairs  = cursor + (size_t)N_CENTERS * padc;

    hipMemsetAsync(cursor, 0, (size_t)N_CENTERS * padc * sizeof(int), stream);
    const int nb = (N_PAIRS + 255) / 256;
    scatter_k<<<nb, 256, 0, stream>>>(didx, species, cursor, pairs, cap, padc);
    accum_k  <<<N_CENTERS, 320, 0, stream>>>(vec0, vec1, vec2, vec3, W,
                                             cursor, pairs, out, cap, padc);
}

// Round 4
// 424.224 us; speedup vs baseline: 1.1562x; 1.0174x over previous
//
#include <hip/hip_runtime.h>

// Problem constants (fixed by setup_inputs)
#define N_PAIRS   300000
#define N_CENTERS 10000
#define N_FEAT    1280   // sum over l of (2l+1)*4*20 = 16*80

// -------- phase A: capacity-bucket counting sort --------
// cursor[c*padc] counts pairs of center c; pairs[c*cap + pos] = p | s<<20.

__global__ void scatter_k(const int* __restrict__ didx, const int* __restrict__ species,
                          int* __restrict__ cursor, int* __restrict__ pairs,
                          int cap, int padc) {
    int p = blockIdx.x * blockDim.x + threadIdx.x;
    if (p < N_PAIRS) {
        int c = didx[p];
        int pos = atomicAdd(&cursor[c * padc], 1);
        if (pos < cap) pairs[c * cap + pos] = p | (species[p] << 20);  // p < 2^19, s < 4
    }
}

// -------- phase B: one block per center --------
// thread t = (j = t/80, u = t%80). Per round of 4 pairs, thread (j,u) gathers
// the DISTINCT float4 chunk u of pair i+j (1 KB distinct per wave-instruction
// -> 4x fewer TA lane-addresses than R3), and accumulates it into all 4
// pseudo channels. Pair words + per-pair weight float4 staged in LDS once per
// block; partial sums over j reduced through LDS at the end.

__global__ __launch_bounds__(320) void accum_k(
    const float* __restrict__ vec0, const float* __restrict__ vec1,
    const float* __restrict__ vec2, const float* __restrict__ vec3,
    const float* __restrict__ W,
    const int* __restrict__ cursor, const int* __restrict__ pairs,
    float* __restrict__ out, int cap, int padc) {
    __shared__ int    lds_pk[320];
    __shared__ float4 lds_w4[320];
    __shared__ float4 lds_red[16 * 80];   // 4 j-copies of the 1280-feature vector

    const int t = threadIdx.x;
    const int c = blockIdx.x;

    int cnt = cursor[c * padc];
    cnt = min(cnt, cap);

    if (t < cnt) {                         // cap <= 320: single staging pass
        int pk = pairs[c * cap + t];
        int s  = (pk >> 20) & 3;
        lds_pk[t] = pk & 0xFFFFF;
        lds_w4[t] = make_float4(W[s], W[4 + s], W[8 + s], W[12 + s]); // W[d][s], d=0..3
    }

    const int j = t / 80;                  // pair slot within a round
    const int u = t - j * 80;              // 0..79: float4 chunk of the 320-float row

    const float4* src4; int s4len, foff;
    if (u < 5)       { src4 = (const float4*)vec0; s4len = 5;  foff = u;      }
    else if (u < 20) { src4 = (const float4*)vec1; s4len = 15; foff = u - 5;  }
    else if (u < 45) { src4 = (const float4*)vec2; s4len = 25; foff = u - 20; }
    else             { src4 = (const float4*)vec3; s4len = 35; foff = u - 45; }

    float4 a0 = make_float4(0.f, 0.f, 0.f, 0.f);
    float4 a1 = a0, a2 = a0, a3 = a0;

    __syncthreads();

    for (int i = 0; i < cnt; i += 16) {    // 4 rounds x 4 pairs per iteration
        float4 vv[4], ww[4];
        #pragma unroll
        for (int r = 0; r < 4; ++r) {
            const int q  = i + r * 4 + j;
            const int qq = min(q, cnt - 1);          // clamp tail (cnt >= 1 here)
            const int p_ = lds_pk[qq];
            float4 w = lds_w4[qq];
            if (q >= cnt) w = make_float4(0.f, 0.f, 0.f, 0.f);
            ww[r] = w;
            vv[r] = src4[(long long)p_ * s4len + foff];
        }
        #pragma unroll
        for (int r = 0; r < 4; ++r) {
            const float4 v = vv[r], w = ww[r];
            a0.x += v.x * w.x; a0.y += v.y * w.x; a0.z += v.z * w.x; a0.w += v.w * w.x;
            a1.x += v.x * w.y; a1.y += v.y * w.y; a1.z += v.z * w.y; a1.w += v.w * w.y;
            a2.x += v.x * w.z; a2.y += v.y * w.z; a2.z += v.z * w.z; a2.w += v.w * w.z;
            a3.x += v.x * w.w; a3.y += v.y * w.w; a3.z += v.z * w.w; a3.w += v.w * w.w;
        }
    }

    // reduce the 4 j-partials through LDS
    lds_red[(j * 4 + 0) * 80 + u] = a0;
    lds_red[(j * 4 + 1) * 80 + u] = a1;
    lds_red[(j * 4 + 2) * 80 + u] = a2;
    lds_red[(j * 4 + 3) * 80 + u] = a3;
    __syncthreads();

    const float4 r0 = lds_red[(0 * 4 + j) * 80 + u];
    const float4 r1 = lds_red[(1 * 4 + j) * 80 + u];
    const float4 r2 = lds_red[(2 * 4 + j) * 80 + u];
    const float4 r3 = lds_red[(3 * 4 + j) * 80 + u];
    const float4 res = make_float4(r0.x + r1.x + r2.x + r3.x,
                                   r0.y + r1.y + r2.y + r3.y,
                                   r0.z + r1.z + r2.z + r3.z,
                                   r0.w + r1.w + r2.w + r3.w);

    // output feature index for (d = j, g0 = 4u)
    const int g0 = 4 * u;
    int fb, vb;
    if (g0 < 20)       { fb = 0;   vb = 0;   }
    else if (g0 < 80)  { fb = 80;  vb = 20;  }
    else if (g0 < 180) { fb = 320; vb = 80;  }
    else               { fb = 720; vb = 180; }
    const int rr = g0 - vb;
    const int cc = rr / 20;
    const int n0 = rr - cc * 20;
    const int f0 = fb + cc * 80 + j * 20 + n0;

    ((float4*)(out + (long long)c * N_FEAT))[f0 >> 2] = res;
}

// -------- launcher --------
extern "C" void kernel_launch(void* const* d_in, const int* in_sizes, int n_in,
                              void* d_out, int out_size, void* d_ws, size_t ws_size,
                              hipStream_t stream) {
    const float* vec0 = (const float*)d_in[0];
    const float* vec1 = (const float*)d_in[1];
    const float* vec2 = (const float*)d_in[2];
    const float* vec3 = (const float*)d_in[3];
    const float* W    = (const float*)d_in[4];
    const int* species = (const int*)d_in[5];
    const int* didx    = (const int*)d_in[6];
    float* out = (float*)d_out;

    // bucket capacity + cursor padding from ws_size (fixed across calls ->
    // deterministic, graph-safe). layout: cursor [N_CENTERS*padc] |
    // pairs [N_CENTERS*cap + 32 slack]. cap must stay <= 320 (single-pass LDS
    // staging in accum_k).
    int cap = 256, padc = 16;
    auto need = [](int cap_, int padc_) {
        return ((size_t)N_CENTERS * padc_ + (size_t)N_CENTERS * cap_ + 32) * 4;
    };
    if (ws_size < need(256, 16)) { cap = 128; padc = 16; }
    if (ws_size < need(128, 16)) { cap = 128; padc = 1;  }
    if (ws_size < need(128, 1))  { cap = 64;  padc = 1;  }

    int* cursor = (int*)d_ws;
    int* pairs  = cursor + (size_t)N_CENTERS * padc;

    hipMemsetAsync(cursor, 0, (size_t)N_CENTERS * padc * sizeof(int), stream);
    const int nb = (N_PAIRS + 255) / 256;
    scatter_k<<<nb, 256, 0, stream>>>(didx, species, cursor, pairs, cap, padc);
    accum_k  <<<N_CENTERS, 320, 0, stream>>>(vec0, vec1, vec2, vec3, W,
                                             cursor, pairs, out, cap, padc);
}